// Round 14
// baseline (2351.044 us; speedup 1.0000x reference)
//
#include <hip/hip_runtime.h>
#include <hip/hip_bf16.h>

#define EN 256
#define HN 512
#define BN 64
#define TN 512
#define NBLK 64
#define KCAT 1280        // 256 Wih_hi | 512 Whh_hi | 512 Whh_lo
#define NBUF 8
#define SLOTB 65536      // one h slot: [(p&3)][p>>2][64 samples][8 cols] bf16

typedef __attribute__((ext_vector_type(8))) short short8;
typedef __attribute__((ext_vector_type(4))) short short4v;
typedef __attribute__((ext_vector_type(4))) float f32x4;

#define SCOPE __HIP_MEMORY_SCOPE_AGENT
#define MFMA(A, B, C) __builtin_amdgcn_mfma_f32_16x16x32_bf16((A), (B), (C), 0, 0, 0)

__device__ inline short bf_of(float f) {
  __hip_bfloat16 h = __float2bfloat16(f);
  return *reinterpret_cast<short*>(&h);
}
__device__ inline float f_of_bf(short s) {
  __hip_bfloat16 h = *reinterpret_cast<__hip_bfloat16*>(&s);
  return __bfloat162float(h);
}

// ---------- K0: zero h slot 0 (h_0 = 0) and flags ----------
__global__ __launch_bounds__(256) void zero_kernel(unsigned* hb_u32,
                                                   unsigned* flags) {
  int idx = blockIdx.x * 256 + threadIdx.x;
  if (idx < SLOTB / 4)
    __hip_atomic_store(&hb_u32[idx], 0u, __ATOMIC_RELAXED, SCOPE);
  if (idx < NBLK)
    __hip_atomic_store(&flags[idx], 0u, __ATOMIC_RELAXED, SCOPE);
}

// ---------- K1: weB[t*64+b][k] = bf16(emb[x[b][t]][k]) ----------
__global__ __launch_bounds__(256) void gather_kernel(
    short* __restrict__ weB, const int* __restrict__ x,
    const float* __restrict__ emb) {
  const int t = blockIdx.x;
  const int tid = threadIdx.x;
  const int b = tid >> 2, q = tid & 3;
  const int row = x[b * TN + t];
  const float4* src = (const float4*)(emb + (size_t)row * EN + q * 64);
  short* dst = weB + ((size_t)(t * 64 + b)) * EN + q * 64;
#pragma unroll
  for (int i = 0; i < 16; i++) {
    float4 v = src[i];
    short4v o = { bf_of(v.x), bf_of(v.y), bf_of(v.z), bf_of(v.w) };
    *(short4v*)(dst + i * 4) = o;
  }
}

// ---------- K2: Wall[grow][kc]: kc<256 Wih_hi | <768 Whh_hi | else Whh_lo --
__global__ __launch_bounds__(256) void prep_w_kernel(
    short* __restrict__ Wall, const float* __restrict__ Wih,
    const float* __restrict__ Whh) {
  int idx = blockIdx.x * 256 + threadIdx.x;   // 2048*1280 total
  int grow = idx / KCAT, kc = idx - grow * KCAT;
  float v;
  if (kc < 256) {
    v = Wih[(size_t)grow * EN + kc];
  } else if (kc < 768) {
    v = Whh[(size_t)grow * HN + (kc - 256)];
  } else {
    float f = Whh[(size_t)grow * HN + (kc - 768)];
    v = f - f_of_bf(bf_of(f));                // residual (lo) term
  }
  Wall[idx] = bf_of(v);
}

// ---------- flag poll (ONE wave per block), tight sleep ----------
__device__ __forceinline__ void poll_flags(const unsigned* flags,
                                           unsigned want, int l) {
  bool done = false;
  while (true) {
    if (!done) {
      unsigned v = __hip_atomic_load(&flags[l], __ATOMIC_RELAXED, SCOPE);
      done = (v >= want);
    }
    if (__all(done ? 1 : 0)) break;
    __builtin_amdgcn_s_sleep(1);
  }
  asm volatile("" ::: "memory");   // no hoisting of subsequent loads above
}

// Issue 16 pipelined IC loads (sc1) from 4 bases, NO waitcnt (counted later).
#define HLOAD16_ISSUE                                                       \
  asm volatile(                                                             \
    "global_load_dwordx4 %0,  %16, off sc1\n\t"                             \
    "global_load_dwordx4 %1,  %16, off offset:1024 sc1\n\t"                 \
    "global_load_dwordx4 %2,  %16, off offset:2048 sc1\n\t"                 \
    "global_load_dwordx4 %3,  %16, off offset:3072 sc1\n\t"                 \
    "global_load_dwordx4 %4,  %17, off sc1\n\t"                             \
    "global_load_dwordx4 %5,  %17, off offset:1024 sc1\n\t"                 \
    "global_load_dwordx4 %6,  %17, off offset:2048 sc1\n\t"                 \
    "global_load_dwordx4 %7,  %17, off offset:3072 sc1\n\t"                 \
    "global_load_dwordx4 %8,  %18, off sc1\n\t"                             \
    "global_load_dwordx4 %9,  %18, off offset:1024 sc1\n\t"                 \
    "global_load_dwordx4 %10, %18, off offset:2048 sc1\n\t"                 \
    "global_load_dwordx4 %11, %18, off offset:3072 sc1\n\t"                 \
    "global_load_dwordx4 %12, %19, off sc1\n\t"                             \
    "global_load_dwordx4 %13, %19, off offset:1024 sc1\n\t"                 \
    "global_load_dwordx4 %14, %19, off offset:2048 sc1\n\t"                 \
    "global_load_dwordx4 %15, %19, off offset:3072 sc1"                     \
    : "=&v"(hv0), "=&v"(hv1), "=&v"(hv2),  "=&v"(hv3),                      \
      "=&v"(hv4), "=&v"(hv5), "=&v"(hv6),  "=&v"(hv7),                      \
      "=&v"(hv8), "=&v"(hv9), "=&v"(hv10), "=&v"(hv11),                     \
      "=&v"(hv12), "=&v"(hv13), "=&v"(hv14), "=&v"(hv15)                    \
    : "v"(hb0), "v"(hb1), "v"(hb2), "v"(hb3) : "memory")

#define WAIT_HALF                                                           \
  do {                                                                      \
    asm volatile("s_waitcnt vmcnt(8)"                                       \
                 : "+v"(hv0), "+v"(hv1), "+v"(hv2), "+v"(hv3),              \
                   "+v"(hv4), "+v"(hv5), "+v"(hv6), "+v"(hv7)               \
                 :: "memory");                                              \
    __builtin_amdgcn_sched_barrier(0);                                      \
  } while (0)

#define WAIT_ALL                                                            \
  do {                                                                      \
    asm volatile("s_waitcnt vmcnt(0)"                                       \
                 : "+v"(hv8), "+v"(hv9), "+v"(hv10), "+v"(hv11),            \
                   "+v"(hv12), "+v"(hv13), "+v"(hv14), "+v"(hv15)           \
                 :: "memory");                                              \
    __builtin_amdgcn_sched_barrier(0);                                      \
  } while (0)

// ---------- scan: 64 blocks x 512 thr, block owns h-cols [8*blk, 8*blk+8) --
__global__ __launch_bounds__(512, 1) void scan_kernel(
    const short* __restrict__ weB, const short* __restrict__ Wall,
    char* __restrict__ hb, const int* __restrict__ length,
    const float* __restrict__ bih, const float* __restrict__ bhh,
    const float* __restrict__ Wcls, const float* __restrict__ bcls,
    float* __restrict__ part, unsigned* flags, float* __restrict__ out) {
  __shared__ float gl[32][65];            // gate rows r = type*8+jj, col b
  __shared__ __align__(16) short hstage[BN][8];
  const int tid = threadIdx.x;
  const int l = tid & 63, w = tid >> 6;
  const int bid = blockIdx.x;
  const int j0 = bid * 8;

  // --- MFMA role: wave w -> C rows [rhalf,+16), cols [btile,+16)
  const int btile = (w & 3) * 16;
  const int rhalf = (w >> 2) * 16;

  short8 aH[24], aL[16];
  {
    int r = rhalf + (l & 15);
    int grow = (r >> 3) * HN + j0 + (r & 7);
    const short* wp = Wall + (size_t)grow * KCAT + 8 * (l >> 4);
#pragma unroll
    for (int kk = 0; kk < 24; kk++) aH[kk] = *(const short8*)(wp + kk * 32);
#pragma unroll
    for (int kk = 0; kk < 16; kk++) aL[kk] = *(const short8*)(wp + 768 + kk * 32);
  }

  // --- elementwise role: thread -> (jj = w, b = l)
  const int jj = w, b = l;
  float bias[4];
#pragma unroll
  for (int ty = 0; ty < 4; ty++) {
    int grow = ty * HN + j0 + jj;
    bias[ty] = bih[grow] + bhh[grow];
  }
  const int len = length[b];
  float c = 0.f, fmx = -INFINITY;

  // consumer base within a slot: (l>>4)*16384 + sample*16
  const int cons_off = (l >> 4) * 16384 + (btile + (l & 15)) * 16;
  // producer store offset within a slot: (bid&3)*16384 + (bid>>2)*1024 + l*16
  const int prod_off = (bid & 3) * 16384 + (bid >> 2) * 1024 + l * 16;

  for (int t = 0; t < TN; t++) {
    // ---- x side: loads + MFMAs BEFORE the poll (no h dependency) ----
    const short* xrow = weB + ((size_t)(t * 64 + btile + (l & 15))) * EN + 8 * (l >> 4);
    short8 xf[8];
#pragma unroll
    for (int kk = 0; kk < 8; kk++) xf[kk] = *(const short8*)(xrow + kk * 32);
    f32x4 accH = {0.f, 0.f, 0.f, 0.f}, accL = {0.f, 0.f, 0.f, 0.f};
#pragma unroll
    for (int kk = 0; kk < 8; kk++)
      accH = MFMA(aH[kk], xf[kk], accH);

    // ---- wait: SINGLE wave polls ----
    if (w == 0) poll_flags(flags, (unsigned)t, l);
    __syncthreads();                      // (c) release block after poll

    // ---- h side: 16 loads issued once; counted waits overlap MFMA ----
    const char* hb0 = hb + (size_t)(t & 7) * SLOTB + cons_off;
    const char* hb1 = hb0 + 4096;
    const char* hb2 = hb0 + 8192;
    const char* hb3 = hb0 + 12288;
    short8 hv0, hv1, hv2, hv3, hv4, hv5, hv6, hv7;
    short8 hv8, hv9, hv10, hv11, hv12, hv13, hv14, hv15;
    HLOAD16_ISSUE;
    WAIT_HALF;                            // first 8 chunks landed
    accH = MFMA(aH[8],  hv0,  accH);  accL = MFMA(aL[0],  hv0,  accL);
    accH = MFMA(aH[9],  hv1,  accH);  accL = MFMA(aL[1],  hv1,  accL);
    accH = MFMA(aH[10], hv2,  accH);  accL = MFMA(aL[2],  hv2,  accL);
    accH = MFMA(aH[11], hv3,  accH);  accL = MFMA(aL[3],  hv3,  accL);
    accH = MFMA(aH[12], hv4,  accH);  accL = MFMA(aL[4],  hv4,  accL);
    accH = MFMA(aH[13], hv5,  accH);  accL = MFMA(aL[5],  hv5,  accL);
    accH = MFMA(aH[14], hv6,  accH);  accL = MFMA(aL[6],  hv6,  accL);
    accH = MFMA(aH[15], hv7,  accH);  accL = MFMA(aL[7],  hv7,  accL);
    WAIT_ALL;                             // remaining 8 chunks landed
    accH = MFMA(aH[16], hv8,  accH);  accL = MFMA(aL[8],  hv8,  accL);
    accH = MFMA(aH[17], hv9,  accH);  accL = MFMA(aL[9],  hv9,  accL);
    accH = MFMA(aH[18], hv10, accH);  accL = MFMA(aL[10], hv10, accL);
    accH = MFMA(aH[19], hv11, accH);  accL = MFMA(aL[11], hv11, accL);
    accH = MFMA(aH[20], hv12, accH);  accL = MFMA(aL[12], hv12, accL);
    accH = MFMA(aH[21], hv13, accH);  accL = MFMA(aL[13], hv13, accL);
    accH = MFMA(aH[22], hv14, accH);  accL = MFMA(aL[14], hv14, accL);
    accH = MFMA(aH[23], hv15, accH);  accL = MFMA(aL[15], hv15, accL);

#pragma unroll
    for (int q = 0; q < 4; q++) {         // C/D: col = lane&15, row = (lane>>4)*4+q
      int r = rhalf + (l >> 4) * 4 + q;
      gl[r][btile + (l & 15)] = accH[q] + accL[q];
    }
    __syncthreads();                      // (a) gates visible to nonlin threads
    {
      float gi = gl[0 + jj][b] + bias[0];
      float gf = gl[8 + jj][b] + bias[1];
      float gg = gl[16 + jj][b] + bias[2];
      float go = gl[24 + jj][b] + bias[3];
      float si = 1.f / (1.f + __expf(-gi));
      float sf = 1.f / (1.f + __expf(-gf));
      float so = 1.f / (1.f + __expf(-go));
      float tg = 2.f / (1.f + __expf(-2.f * gg)) - 1.f;
      c = sf * c + si * tg;
      float tc = 2.f / (1.f + __expf(-2.f * c)) - 1.f;
      float h = so * tc;
      hstage[b][jj] = bf_of(h);
      if (t < len) fmx = fmaxf(fmx, h);
    }
    __syncthreads();                      // (b) hstage complete
    if (w == 0) {                         // wave 0: ONE contiguous 16B store/lane
      short8 val = *(const short8*)&hstage[l][0];
      char* dp = hb + (size_t)((t + 1) & 7) * SLOTB + prod_off;
      asm volatile("global_store_dwordx4 %0, %1, off sc1"
                   :: "v"(dp), "v"(val) : "memory");
      asm volatile("s_waitcnt vmcnt(0)" ::: "memory");
      if (l == 0)
        __hip_atomic_store(&flags[bid], (unsigned)(t + 1),
                           __ATOMIC_RELAXED, SCOPE);
    }
    // WAR: slot (t+1)&7 clobbers h_{t-7}; poll(t) certified all blocks
    // published h_t => consumed h_{t-1} => consumed h_{t-7}. Safe.
  }

  // --- classifier partials ---
  gl[jj][b]      = fmx * Wcls[j0 + jj];
  gl[8 + jj][b]  = fmx * Wcls[HN + j0 + jj];
  __syncthreads();
  if (tid < 128) {
    int cls = tid >> 6, bb = tid & 63;
    float s = 0.f;
#pragma unroll
    for (int q = 0; q < 8; q++) s += gl[cls * 8 + q][bb];
    __hip_atomic_store(&part[(size_t)bid * 128 + cls * 64 + bb], s,
                       __ATOMIC_RELAXED, SCOPE);
  }
  __syncthreads();
  asm volatile("s_waitcnt vmcnt(0)" ::: "memory");
  if (tid == 0)
    __hip_atomic_store(&flags[bid], (unsigned)(TN + 1), __ATOMIC_RELAXED, SCOPE);
  if (bid == 0) {
    if (w == 0) poll_flags(flags, (unsigned)(TN + 1), l);
    __syncthreads();
    if (tid < 128) {
      int cls = tid >> 6, bb = tid & 63;
      float s = bcls[cls];
#pragma unroll 8
      for (int k = 0; k < NBLK; k++)
        s += __uint_as_float(__hip_atomic_load(
            (const unsigned*)&part[(size_t)k * 128 + cls * 64 + bb],
            __ATOMIC_RELAXED, SCOPE));
      out[bb * 2 + cls] = s;
    }
  }
}

extern "C" void kernel_launch(void* const* d_in, const int* in_sizes, int n_in,
                              void* d_out, int out_size, void* d_ws, size_t ws_size,
                              hipStream_t stream) {
  const int*   x    = (const int*)d_in[0];
  const int*   len  = (const int*)d_in[1];
  const float* emb  = (const float*)d_in[2];
  const float* Wih  = (const float*)d_in[3];
  const float* Whh  = (const float*)d_in[4];
  const float* bih  = (const float*)d_in[5];
  const float* bhh  = (const float*)d_in[6];
  const float* Wcls = (const float*)d_in[7];
  const float* bcls = (const float*)d_in[8];
  float* out = (float*)d_out;

  char* ws = (char*)d_ws;
  short* weB  = (short*)ws;                                   // 16,777,216 B
  short* Wall = (short*)(ws + 16777216ull);                   //  5,242,880 B
  char*  hb   = ws + 16777216ull + 5242880;                   // 8*64KB = 524,288 B
  float* part = (float*)(ws + 16777216ull + 5242880 + 524288);         // 32 KB
  unsigned* flagp = (unsigned*)(ws + 16777216ull + 5242880 + 524288 + 32768);

  zero_kernel<<<dim3(64), dim3(256), 0, stream>>>((unsigned*)hb, flagp);
  gather_kernel<<<dim3(TN), dim3(256), 0, stream>>>(weB, x, emb);
  prep_w_kernel<<<dim3((2048 * KCAT) / 256), dim3(256), 0, stream>>>(Wall, Wih, Whh);

  void* args[] = { (void*)&weB, (void*)&Wall, (void*)&hb, (void*)&len,
                   (void*)&bih, (void*)&bhh, (void*)&Wcls, (void*)&bcls,
                   (void*)&part, (void*)&flagp, (void*)&out };
  hipLaunchCooperativeKernel((void*)scan_kernel, dim3(NBLK), dim3(512),
                             args, 0, stream);
}